// Round 11
// baseline (1985.993 us; speedup 1.0000x reference)
//
#include <hip/hip_runtime.h>

#define B_  16
#define T_  1024
#define D_  512
#define H_  8
#define L_  6
#define V_  96
#define HS_ 64
#define FF_ 2048
#define BT_ (B_*T_)
#define QKS 1024   // row stride (shorts) of the fused Q|K activation buffer

typedef __attribute__((ext_vector_type(8))) short bf16x8;
typedef __attribute__((ext_vector_type(4))) float f32x4;

typedef __attribute__((address_space(3))) unsigned int lds_u32_t;
typedef const __attribute__((address_space(1))) unsigned int glb_u32_t;

__device__ __forceinline__ void gload16(const unsigned short* g, unsigned short* l) {
  __builtin_amdgcn_global_load_lds((glb_u32_t*)g, (lds_u32_t*)l, 16, 0, 0);
}

__device__ __forceinline__ unsigned short f2b(float f) {
  unsigned u = __float_as_uint(f);
  unsigned r = (u + 0x7FFFu + ((u >> 16) & 1u)) >> 16;
  return (unsigned short)r;
}

__global__ void zero_kernel(float* p) { p[0] = 0.f; }

// ---------------- embedding ----------------
__global__ __launch_bounds__(128) void embed_kernel(const int* __restrict__ idx,
    const float* __restrict__ tok, const float* __restrict__ pos, float* __restrict__ x) {
  int bt = blockIdx.x;
  int t  = bt & (T_ - 1);
  int id = idx[bt];
  if (id < 0) id = 0; if (id > V_ - 1) id = V_ - 1;
  int d  = threadIdx.x * 4;
  float4 tv = *(const float4*)(tok + (size_t)id * D_ + d);
  float4 pv = *(const float4*)(pos + (size_t)t  * D_ + d);
  float4 o = {tv.x + pv.x, tv.y + pv.y, tv.z + pv.z, tv.w + pv.w};
  *(float4*)(x + (size_t)bt * D_ + d) = o;
}

// ---------------- tiled transpose + f32->bf16: dst[C][R] = src[R][C] ----------------
__global__ __launch_bounds__(256) void transpose_cvt(const float* __restrict__ src,
    unsigned short* __restrict__ dst, int R, int C, long sstride, long dstride,
    int zper, long zouter) {
  __shared__ float t[32][33];
  const float* s = src + (size_t)blockIdx.z * sstride;
  unsigned short* d = dst + (size_t)(blockIdx.z / zper) * zouter
                          + (size_t)(blockIdx.z % zper) * dstride;
  int r0 = blockIdx.y * 32, c0 = blockIdx.x * 32;
  int tr = threadIdx.x >> 5, tc = threadIdx.x & 31;
#pragma unroll
  for (int i = 0; i < 4; ++i)
    t[tr + i * 8][tc] = s[(size_t)(r0 + tr + i * 8) * C + c0 + tc];
  __syncthreads();
#pragma unroll
  for (int i = 0; i < 4; ++i)
    d[(size_t)(c0 + tr + i * 8) * R + r0 + tc] = f2b(t[tc][tr + i * 8]);
}

// ---------------- layernorm: one wave per row, vectorized ----------------
template<bool BF16OUT>
__global__ __launch_bounds__(256) void ln_kernel(const float* __restrict__ x,
    const float* __restrict__ s, const float* __restrict__ b, void* __restrict__ outv) {
  int wave = threadIdx.x >> 6;
  int lane = threadIdx.x & 63;
  int r = blockIdx.x * 4 + wave;
  const float* xr = x + (size_t)r * D_ + lane * 8;
  float4 va = *(const float4*)(xr);
  float4 vb = *(const float4*)(xr + 4);
  float vals[8] = {va.x, va.y, va.z, va.w, vb.x, vb.y, vb.z, vb.w};
  float sum = 0.f;
#pragma unroll
  for (int j = 0; j < 8; ++j) sum += vals[j];
#pragma unroll
  for (int o = 32; o > 0; o >>= 1) sum += __shfl_xor(sum, o, 64);
  float mean = sum * (1.f / D_);
  float vs = 0.f;
#pragma unroll
  for (int j = 0; j < 8; ++j) { float d = vals[j] - mean; vs += d * d; }
#pragma unroll
  for (int o = 32; o > 0; o >>= 1) vs += __shfl_xor(vs, o, 64);
  float rstd = rsqrtf(vs * (1.f / D_) + 1e-5f);
  float4 sa = *(const float4*)(s + lane * 8);
  float4 sb = *(const float4*)(s + lane * 8 + 4);
  float4 ba = *(const float4*)(b + lane * 8);
  float4 bb = *(const float4*)(b + lane * 8 + 4);
  float sc[8] = {sa.x, sa.y, sa.z, sa.w, sb.x, sb.y, sb.z, sb.w};
  float bc[8] = {ba.x, ba.y, ba.z, ba.w, bb.x, bb.y, bb.z, bb.w};
  float v[8];
#pragma unroll
  for (int j = 0; j < 8; ++j) v[j] = (vals[j] - mean) * rstd * sc[j] + bc[j];
  if (BF16OUT) {
    uint4 pk;
    pk.x = (unsigned)f2b(v[0]) | ((unsigned)f2b(v[1]) << 16);
    pk.y = (unsigned)f2b(v[2]) | ((unsigned)f2b(v[3]) << 16);
    pk.z = (unsigned)f2b(v[4]) | ((unsigned)f2b(v[5]) << 16);
    pk.w = (unsigned)f2b(v[6]) | ((unsigned)f2b(v[7]) << 16);
    *(uint4*)((unsigned short*)outv + (size_t)r * D_ + lane * 8) = pk;
  } else {
    float* op = (float*)outv + (size_t)r * D_ + lane * 8;
    *(float4*)(op)     = make_float4(v[0], v[1], v[2], v[3]);
    *(float4*)(op + 4) = make_float4(v[4], v[5], v[6], v[7]);
  }
}

// ---------------- bf16 MFMA GEMM: C[M,N] (+)= A[M,K] @ Bt[N,K]^T ----------------
// R11: WG2 in-block split-K for proj/FF2. 512 threads = 2 wave-groups; group g
// runs the proven 2-phase loop over K-half g with its OWN LDS double-buffer
// (barriers align: same nsteps both groups). Partials combine through a 32KB
// lane-contiguous LDS buffer -> ZERO extra HBM traffic (R9's atomic combine was
// HBM-RMW-bound), tile shape preserved (R6's failure mode), plain barriers only
// (R5's failure mode). Halves the number of barrier-drain intervals and doubles
// waves/CU (8->16). LDS 80KB -> exactly 2 blocks/CU = the grid's 2/CU.
// QKV reverted to R8's MT=128 (R10's MT=64 QKV measured -19us regression).
// OUTMODE: 0 = f32 [M][ldc], 1 = bf16 [M][ldc],
//          3 = fused QKV: cols 0..1023 -> bf16 [M][QKS], cols 1024..1535 -> Vt
#define BK 32
template<bool ACC, bool RELU, bool BIAS, int OUTMODE, int MT, int NT, bool WG2>
__global__ __launch_bounds__(WG2 ? 512 : 256) void mfma_gemm(
    const unsigned short* __restrict__ A,
    const unsigned short* __restrict__ Bt,
    const float* __restrict__ bias,
    void* __restrict__ Cv, void* __restrict__ Cv2,
    int K, int ldc) {
  static_assert(!WG2 || (OUTMODE == 0 && ACC && !RELU), "WG2 path is f32-ACC only");
  constexpr int NI = (MT == 128) ? 4 : (NT == 128 ? 2 : 1);
  constexpr int WN = (MT == 128) ? 64 : (NT == 128 ? 32 : 16);
  constexpr int NG = WG2 ? 2 : 1;
  __shared__ unsigned short Al[NG][2][MT * BK];
  __shared__ unsigned short Bl[NG][2][NT * BK];
  __shared__ float red[WG2 ? (MT * NT) : 4];
  const int nwg = gridDim.x * gridDim.y;
  const int flat = blockIdx.x + gridDim.x * blockIdx.y;
  const int swz = (flat & 7) * (nwg >> 3) + (flat >> 3);
  const int bx = swz / gridDim.y;
  const int by = swz % gridDim.y;
  const int m0 = bx * MT, n0 = by * NT;
  const int tid = threadIdx.x;
  const int lane = tid & 63, wave = tid >> 6;
  const int grp = WG2 ? (wave >> 2) : 0;          // wave group (K-half)
  const int wl  = WG2 ? (wave & 3) : wave;        // wave index within group
  const int wy = (MT == 128) ? (wl >> 1) : 0;
  const int wx = (MT == 128) ? (wl & 1) : wl;
  const int l15 = lane & 15, quad = lane >> 4;

  const int sbase = wl * 1024;
  const int soff  = sbase + lane * 16;
  const int r0 = soff >> 6, c0e = (soff & 63) >> 1;
  const int r1 = r0 + 64;
  const int ls = sbase >> 1;
  const int kb = grp * (K / NG);
  const unsigned short* gA0 = A  + (size_t)(m0 + r0) * K + c0e + kb;
  const unsigned short* gA1 = A  + (size_t)(m0 + r1) * K + c0e + kb;  // MT==128 only
  const unsigned short* gB0 = Bt + (size_t)(n0 + r0) * K + c0e + kb;
  const unsigned short* gB1 = Bt + (size_t)(n0 + r1) * K + c0e + kb;  // NT==128 only

  auto stage = [&](int buf, int k0) {
    gload16(gA0 + k0, &Al[grp][buf][ls]);
    if constexpr (MT == 128) gload16(gA1 + k0, &Al[grp][buf][ls + 2048]);
    gload16(gB0 + k0, &Bl[grp][buf][ls]);
    if constexpr (NT == 128) gload16(gB1 + k0, &Bl[grp][buf][ls + 2048]);
  };

  f32x4 acc[4][NI];
  const f32x4 z4 = {0.f, 0.f, 0.f, 0.f};
#pragma unroll
  for (int mi = 0; mi < 4; ++mi)
#pragma unroll
    for (int ni = 0; ni < NI; ++ni) acc[mi][ni] = z4;

  stage(0, 0);
  __syncthreads();

  const int nsteps = K / NG / BK;
  int cur = 0;
  for (int s = 0; s < nsteps; ++s) {
    if (s + 1 < nsteps) stage(cur ^ 1, (s + 1) * BK);
    bf16x8 af[4], bfr[NI];
#pragma unroll
    for (int mi = 0; mi < 4; ++mi)
      af[mi] = *(const bf16x8*)(&Al[grp][cur][(wy * 64 + mi * 16 + l15) * BK + quad * 8]);
#pragma unroll
    for (int ni = 0; ni < NI; ++ni)
      bfr[ni] = *(const bf16x8*)(&Bl[grp][cur][(wx * WN + ni * 16 + l15) * BK + quad * 8]);
#pragma unroll
    for (int mi = 0; mi < 4; ++mi)
#pragma unroll
      for (int ni = 0; ni < NI; ++ni)
        acc[mi][ni] = __builtin_amdgcn_mfma_f32_16x16x32_bf16(af[mi], bfr[ni], acc[mi][ni], 0, 0, 0);
    if (s + 1 < nsteps) {
      __syncthreads();
      cur ^= 1;
    }
  }

  if constexpr (WG2) {
    // combine K-half partials through LDS (lane-contiguous slots, conflict-free)
    if (grp == 1) {
#pragma unroll
      for (int mi = 0; mi < 4; ++mi)
#pragma unroll
        for (int ni = 0; ni < NI; ++ni)
#pragma unroll
          for (int r = 0; r < 4; ++r)
            red[((mi * NI + ni) * 4 + r) * 256 + wl * 64 + lane] = acc[mi][ni][r];
    }
    __syncthreads();
    if (grp == 1) return;
#pragma unroll
    for (int mi = 0; mi < 4; ++mi)
#pragma unroll
      for (int ni = 0; ni < NI; ++ni)
#pragma unroll
        for (int r = 0; r < 4; ++r)
          acc[mi][ni][r] += red[((mi * NI + ni) * 4 + r) * 256 + wl * 64 + lane];
  }

#pragma unroll
  for (int mi = 0; mi < 4; ++mi) {
    int row0 = m0 + wy * 64 + mi * 16 + quad * 4;
#pragma unroll
    for (int ni = 0; ni < NI; ++ni) {
      int col = n0 + wx * WN + ni * 16 + l15;
      float bb = BIAS ? bias[col] : 0.f;
#pragma unroll
      for (int r = 0; r < 4; ++r) {
        float v = acc[mi][ni][r] + bb;
        if (RELU) v = fmaxf(v, 0.f);
        int row = row0 + r;
        if (OUTMODE == 3) {
          if (col < 1024) {
            ((unsigned short*)Cv)[(size_t)row * QKS + col] = f2b(v);
          } else {
            int vcol = col - 1024;
            int b = row >> 10, t = row & (T_ - 1);
            int h = vcol >> 6, hs = vcol & 63;
            ((unsigned short*)Cv2)[((size_t)((b * H_ + h) * HS_ + hs)) * T_ + t] = f2b(v);
          }
        } else {
          size_t off = (size_t)row * ldc + col;
          if (ACC) v += ((const float*)Cv)[off];
          if (OUTMODE == 1) ((unsigned short*)Cv)[off] = f2b(v);
          else              ((float*)Cv)[off] = v;
        }
      }
    }
  }
}

// ---------------- MFMA flash attention, no-max softmax ----------------
// Fold-paired (17 uniform iterations/block). P conversion via paired
// v_cvt_pk_bf16_f32; denominator accumulates unrounded f32 p.
#define PSTR 72
__global__ __launch_bounds__(256) void attn_mfma(const unsigned short* __restrict__ q,
    const unsigned short* __restrict__ k, const unsigned short* __restrict__ vt,
    unsigned short* __restrict__ o) {
  __shared__ unsigned short Pbuf[2][64 * PSTR];
  __shared__ float Lsum[4][64];
  const int bh = blockIdx.y;
  const int b = bh >> 3, hh = bh & 7;
  const int tid = threadIdx.x;
  const int lane = tid & 63, w = tid >> 6;
  const int l15 = lane & 15, quad = lane >> 4;
  const float CEXP = 0.044194173824159216f * 1.4426950408889634f;  // scale*log2(e)

  const unsigned short* kbase = k  + (size_t)(b * T_ + w * 16 + l15) * QKS + hh * HS_ + quad * 8;
  const unsigned short* vbase = vt + ((size_t)(bh * HS_ + w * 16 + l15)) * T_ + quad * 8;
  const int gc = w * 16 + l15;
  const f32x4 z4 = {0.f, 0.f, 0.f, 0.f};

  for (int pass = 0; pass < 2; ++pass) {
    const int qt = pass ? (int)blockIdx.x : (T_ / 64 - 1 - (int)blockIdx.x);

    bf16x8 qf[4][2];
#pragma unroll
    for (int mi = 0; mi < 4; ++mi)
#pragma unroll
      for (int c = 0; c < 2; ++c)
        qf[mi][c] = *(const bf16x8*)(q + (size_t)(b * T_ + qt * 64 + mi * 16 + l15) * QKS
                                       + hh * HS_ + c * 32 + quad * 8);

    f32x4 oacc[4];
    float psum[4][4];
#pragma unroll
    for (int mi = 0; mi < 4; ++mi) {
      oacc[mi] = z4;
#pragma unroll
      for (int r = 0; r < 4; ++r) psum[mi][r] = 0.f;
    }

    bf16x8 kf[2], vf[2];
#pragma unroll
    for (int c = 0; c < 2; ++c) {
      kf[c] = *(const bf16x8*)(kbase + c * 32);
      vf[c] = *(const bf16x8*)(vbase + c * 32);
    }

    for (int kt = 0; kt <= qt; ++kt) {
      const int ktn = (kt < qt) ? kt + 1 : qt;
      bf16x8 kfn[2], vfn[2];
#pragma unroll
      for (int c = 0; c < 2; ++c) {
        kfn[c] = *(const bf16x8*)(kbase + (size_t)ktn * 64 * QKS + c * 32);
        vfn[c] = *(const bf16x8*)(vbase + ktn * 64 + c * 32);
      }

      f32x4 s[4];
#pragma unroll
      for (int mi = 0; mi < 4; ++mi) s[mi] = z4;
      __builtin_amdgcn_s_setprio(1);
#pragma unroll
      for (int c = 0; c < 2; ++c)
#pragma unroll
        for (int mi = 0; mi < 4; ++mi)
          s[mi] = __builtin_amdgcn_mfma_f32_16x16x32_bf16(qf[mi][c], kf[c], s[mi], 0, 0, 0);
      __builtin_amdgcn_s_setprio(0);

      unsigned short* pb = Pbuf[kt & 1];
      const bool diag = (kt == qt);
#pragma unroll
      for (int mi = 0; mi < 4; ++mi) {
        const int row0 = mi * 16 + quad * 4;
        float pv_[4];
#pragma unroll
        for (int r = 0; r < 4; ++r) {
          float p = exp2f(s[mi][r] * CEXP);
          if (diag && gc > row0 + r) p = 0.f;
          psum[mi][r] += p;
          pv_[r] = p;
        }
        unsigned pk01, pk23;
        asm("v_cvt_pk_bf16_f32 %0, %1, %2" : "=v"(pk01) : "v"(pv_[0]), "v"(pv_[1]));
        asm("v_cvt_pk_bf16_f32 %0, %1, %2" : "=v"(pk23) : "v"(pv_[2]), "v"(pv_[3]));
        const int base = row0 * PSTR + gc;
        pb[base]            = (unsigned short)(pk01 & 0xFFFFu);
        pb[base + PSTR]     = (unsigned short)(pk01 >> 16);
        pb[base + 2 * PSTR] = (unsigned short)(pk23 & 0xFFFFu);
        pb[base + 3 * PSTR] = (unsigned short)(pk23 >> 16);
      }
      __syncthreads();
      __builtin_amdgcn_s_setprio(1);
#pragma unroll
      for (int c = 0; c < 2; ++c) {
#pragma unroll
        for (int mi = 0; mi < 4; ++mi) {
          bf16x8 pf = *(const bf16x8*)(&pb[(mi * 16 + l15) * PSTR + c * 32 + quad * 8]);
          oacc[mi] = __builtin_amdgcn_mfma_f32_16x16x32_bf16(pf, vf[c], oacc[mi], 0, 0, 0);
        }
      }
      __builtin_amdgcn_s_setprio(0);
#pragma unroll
      for (int c = 0; c < 2; ++c) { kf[c] = kfn[c]; vf[c] = vfn[c]; }
    }

#pragma unroll
    for (int mi = 0; mi < 4; ++mi)
#pragma unroll
      for (int r = 0; r < 4; ++r) {
#pragma unroll
        for (int off = 1; off < 16; off <<= 1)
          psum[mi][r] += __shfl_xor(psum[mi][r], off, 64);
      }
    if (l15 == 0) {
#pragma unroll
      for (int mi = 0; mi < 4; ++mi)
#pragma unroll
        for (int r = 0; r < 4; ++r)
          Lsum[w][mi * 16 + quad * 4 + r] = psum[mi][r];
    }
    __syncthreads();
#pragma unroll
    for (int mi = 0; mi < 4; ++mi)
#pragma unroll
      for (int r = 0; r < 4; ++r) {
        int row = mi * 16 + quad * 4 + r;
        float inv = 1.f / (Lsum[0][row] + Lsum[1][row] + Lsum[2][row] + Lsum[3][row]);
        o[(size_t)(b * T_ + qt * 64 + row) * D_ + hh * HS_ + w * 16 + l15] =
            f2b(oacc[mi][r] * inv);
      }
  }
}

// ---------------- f32 tiled GEMM (logits only) ----------------
__global__ __launch_bounds__(256) void gemm_f32_kernel(const float* __restrict__ A, int lda,
    const float* __restrict__ Bw, int ldb, const float* __restrict__ bias,
    float* __restrict__ C, int ldc, int K, int N) {
  __shared__ float As[16][64];
  __shared__ float Bs[16][64];
  int n0 = blockIdx.y * 64;
  int nv = N - n0; if (nv > 64) nv = 64;
  int m0 = blockIdx.x * 64;
  const int tid = threadIdx.x;
  const int tx = tid & 15, ty = tid >> 4;
  const int amm = tid >> 2;
  const int akk = (tid & 3) * 4;
  const int bkk = tid >> 4;
  const int bnn = (tid & 15) * 4;
  float acc[4][4] = {};
  for (int k0 = 0; k0 < K; k0 += 16) {
    float4 av = *(const float4*)(A + (size_t)(m0 + amm) * lda + k0 + akk);
    As[akk + 0][amm] = av.x; As[akk + 1][amm] = av.y;
    As[akk + 2][amm] = av.z; As[akk + 3][amm] = av.w;
    if (bnn < nv) {
      float4 bv = *(const float4*)(Bw + (size_t)(k0 + bkk) * ldb + n0 + bnn);
      Bs[bkk][bnn + 0] = bv.x; Bs[bkk][bnn + 1] = bv.y;
      Bs[bkk][bnn + 2] = bv.z; Bs[bkk][bnn + 3] = bv.w;
    } else {
      Bs[bkk][bnn + 0] = 0.f; Bs[bkk][bnn + 1] = 0.f;
      Bs[bkk][bnn + 2] = 0.f; Bs[bkk][bnn + 3] = 0.f;
    }
    __syncthreads();
#pragma unroll
    for (int kk = 0; kk < 16; ++kk) {
      float4 a4 = *(const float4*)(&As[kk][ty * 4]);
      float4 b4 = *(const float4*)(&Bs[kk][tx * 4]);
      float aa[4] = {a4.x, a4.y, a4.z, a4.w};
      float bb[4] = {b4.x, b4.y, b4.z, b4.w};
#pragma unroll
      for (int i = 0; i < 4; ++i)
#pragma unroll
        for (int j = 0; j < 4; ++j)
          acc[i][j] = fmaf(aa[i], bb[j], acc[i][j]);
    }
    __syncthreads();
  }
  if (tx * 4 < nv) {
#pragma unroll
    for (int i = 0; i < 4; ++i) {
      float* cp = C + (size_t)(m0 + ty * 4 + i) * ldc + n0 + tx * 4;
      float4 st = {acc[i][0] + bias[n0 + tx * 4 + 0], acc[i][1] + bias[n0 + tx * 4 + 1],
                   acc[i][2] + bias[n0 + tx * 4 + 2], acc[i][3] + bias[n0 + tx * 4 + 3]};
      *(float4*)cp = st;
    }
  }
}

// ---------------- loss ----------------
__global__ __launch_bounds__(256) void loss_kernel(const float* __restrict__ logits,
    const int* __restrict__ targets, float* __restrict__ loss_acc) {
  __shared__ float wsum[4];
  int wave = threadIdx.x >> 6, lane = threadIdx.x & 63;
  float local = 0.f;
  for (int r = blockIdx.x * 4 + wave; r < BT_; r += gridDim.x * 4) {
    const float* lr = logits + (size_t)r * V_;
    float v0 = lr[lane];
    float v1 = (lane < 32) ? lr[64 + lane] : -INFINITY;
    float mx = fmaxf(v0, v1);
#pragma unroll
    for (int o = 32; o > 0; o >>= 1) mx = fmaxf(mx, __shfl_xor(mx, o, 64));
    float se = expf(v0 - mx) + ((lane < 32) ? expf(v1 - mx) : 0.f);
#pragma unroll
    for (int o = 32; o > 0; o >>= 1) se += __shfl_xor(se, o, 64);
    if (lane == 0) {
      int tg = targets[r];
      if (tg < 0) tg = 0; if (tg > V_ - 1) tg = V_ - 1;
      local += (mx + logf(se)) - lr[tg];
    }
  }
  if (lane == 0) wsum[wave] = local;
  __syncthreads();
  if (threadIdx.x == 0)
    atomicAdd(loss_acc, wsum[0] + wsum[1] + wsum[2] + wsum[3]);
}

__global__ void loss_finalize_kernel(const float* __restrict__ acc, float* __restrict__ out) {
  out[(size_t)BT_ * V_] = acc[0] * (1.f / BT_);
}

// ---------------- host ----------------
static void* g_ws_fallback = nullptr;

extern "C" void kernel_launch(void* const* d_in, const int* in_sizes, int n_in,
                              void* d_out, int out_size, void* d_ws, size_t ws_size,
                              hipStream_t stream) {
  const int*   idx     = (const int*)d_in[0];
  const int*   targets = (const int*)d_in[1];
  const float* tok  = (const float*)d_in[2];
  const float* pos  = (const float*)d_in[3];
  const float* Wq   = (const float*)d_in[4];
  const float* Wk   = (const float*)d_in[5];
  const float* Wv   = (const float*)d_in[6];
  const float* Wp   = (const float*)d_in[7];
  const float* bp   = (const float*)d_in[8];
  const float* W1   = (const float*)d_in[9];
  const float* b1   = (const float*)d_in[10];
  const float* W2   = (const float*)d_in[11];
  const float* b2   = (const float*)d_in[12];
  const float* l1s  = (const float*)d_in[13];
  const float* l1b  = (const float*)d_in[14];
  const float* l2s  = (const float*)d_in[15];
  const float* l2b  = (const float*)d_in[16];
  const float* lfs  = (const float*)d_in[17];
  const float* lfb  = (const float*)d_in[18];
  const float* Wout = (const float*)d_in[19];
  const float* bout = (const float*)d_in[20];
  float* out = (float*)d_out;   // f32 logits + f32 loss scalar

  const size_t n_x  = (size_t)BT_ * D_;
  const size_t n_wT = 9437184;   // transposed bf16 weights (f32-equiv)
  const size_t need_floats = n_x + n_x + n_x / 2 + n_x / 2 + n_x / 2 +
                             (size_t)BT_ * FF_ / 2 + n_wT + 256;
  const size_t need_bytes  = need_floats * sizeof(float);

  float* ws;
  if (ws_size >= need_bytes) {
    ws = (float*)d_ws;
  } else {
    if (!g_ws_fallback) (void)hipMalloc(&g_ws_fallback, need_bytes);
    ws = (float*)g_ws_fallback;
  }

  size_t off = 0;
  float* x  = ws + off; off += n_x;
  float* qf32 = ws + off; off += n_x;          // Q|K interleaved bf16 [BT][1024]; reused f32 final-LN
  unsigned short* qkb = (unsigned short*)qf32;
  unsigned short* spare = (unsigned short*)(ws + off); off += n_x / 2;
  unsigned short* vtb = (unsigned short*)(ws + off); off += n_x / 2;
  unsigned short* hb  = (unsigned short*)(ws + off); off += n_x / 2;
  unsigned short* ffb = (unsigned short*)(ws + off); off += (size_t)BT_ * FF_ / 2;
  unsigned short* wqkvT = (unsigned short*)(ws + off);   // per-layer [1536][512]
  unsigned short* wpT = wqkvT + (size_t)L_ * 3 * D_ * D_;
  unsigned short* w1T = wpT + (size_t)L_ * D_ * D_;
  unsigned short* w2T = w1T + (size_t)L_ * D_ * FF_;
  off += n_wT;
  float* lacc = ws + off;
  (void)spare;

  const long DD = (long)D_ * D_;          // 262144
  const long L3DD = 3 * DD;               // per-layer combined QKV stride

  zero_kernel<<<1, 1, 0, stream>>>(lacc);
  embed_kernel<<<BT_, 128, 0, stream>>>(idx, tok, pos, x);

  // combined QKV weight transpose: layer l rows [0,512)=Q, [512,1024)=K, [1024,1536)=V
  transpose_cvt<<<dim3(2, 16, 48), 256, 0, stream>>>(Wq, wqkvT,            512, 64, 32768, 32768, 8, L3DD);
  transpose_cvt<<<dim3(2, 16, 48), 256, 0, stream>>>(Wk, wqkvT + DD,       512, 64, 32768, 32768, 8, L3DD);
  transpose_cvt<<<dim3(2, 16, 48), 256, 0, stream>>>(Wv, wqkvT + 2 * DD,   512, 64, 32768, 32768, 8, L3DD);
  transpose_cvt<<<dim3(16, 16, 6), 256, 0, stream>>>(Wp, wpT, 512, 512, 262144, 0, 1, 262144);
  transpose_cvt<<<dim3(64, 16, 6), 256, 0, stream>>>(W1, w1T, 512, 2048, 1048576, 0, 1, 1048576);
  transpose_cvt<<<dim3(16, 64, 6), 256, 0, stream>>>(W2, w2T, 2048, 512, 1048576, 0, 1, 1048576);

  const dim3 gQKV(BT_ / 128, 12);         // R8 config: 768 blocks, 128x128
  const dim3 gF(BT_ / 128, FF_ / 128);    // FF1: 1024 blocks, 128x128
  const dim3 gD64(BT_ / 64, D_ / 128);    // proj/FF2: 512 blocks, 64x128, WG2

  for (int l = 0; l < L_; ++l) {
    ln_kernel<true><<<BT_ / 4, 256, 0, stream>>>(x, l1s + (size_t)l * D_, l1b + (size_t)l * D_, hb);
    mfma_gemm<false, false, false, 3, 128, 128, false><<<gQKV, 256, 0, stream>>>(
        hb, wqkvT + (size_t)l * L3DD, nullptr, qkb, vtb, D_, 0);
    attn_mfma<<<dim3(T_ / 128, B_ * H_), 256, 0, stream>>>(qkb, qkb + 512, vtb, hb);
    mfma_gemm<true, false, true, 0, 64, 128, true><<<gD64, 512, 0, stream>>>(
        hb, wpT + (size_t)l * DD, bp + (size_t)l * D_, x, nullptr, D_, D_);
    ln_kernel<true><<<BT_ / 4, 256, 0, stream>>>(x, l2s + (size_t)l * D_, l2b + (size_t)l * D_, hb);
    mfma_gemm<false, true, true, 1, 128, 128, false><<<gF, 256, 0, stream>>>(
        hb, w1T + (size_t)l * D_ * FF_, b1 + (size_t)l * FF_, ffb, nullptr, D_, FF_);
    mfma_gemm<true, false, true, 0, 64, 128, true><<<gD64, 512, 0, stream>>>(
        ffb, w2T + (size_t)l * FF_ * D_, b2 + (size_t)l * D_, x, nullptr, FF_, D_);
  }

  ln_kernel<false><<<BT_ / 4, 256, 0, stream>>>(x, lfs, lfb, qf32);
  gemm_f32_kernel<<<dim3(BT_ / 64, 2), 256, 0, stream>>>(
      qf32, D_, Wout, V_, bout, out, V_, D_, V_);
  loss_kernel<<<1024, 256, 0, stream>>>(out, targets, lacc);
  loss_finalize_kernel<<<1, 1, 0, stream>>>(lacc, out);
}

// Round 12
// 1830.270 us; speedup vs baseline: 1.0851x; 1.0851x over previous
//
#include <hip/hip_runtime.h>

#define B_  16
#define T_  1024
#define D_  512
#define H_  8
#define L_  6
#define V_  96
#define HS_ 64
#define FF_ 2048
#define BT_ (B_*T_)
#define QKS 1024   // row stride (shorts) of the fused Q|K activation buffer

typedef __attribute__((ext_vector_type(8))) short bf16x8;
typedef __attribute__((ext_vector_type(4))) float f32x4;

typedef __attribute__((address_space(3))) unsigned int lds_u32_t;
typedef const __attribute__((address_space(1))) unsigned int glb_u32_t;

__device__ __forceinline__ void gload16(const unsigned short* g, unsigned short* l) {
  __builtin_amdgcn_global_load_lds((glb_u32_t*)g, (lds_u32_t*)l, 16, 0, 0);
}

__device__ __forceinline__ unsigned short f2b(float f) {
  unsigned u = __float_as_uint(f);
  unsigned r = (u + 0x7FFFu + ((u >> 16) & 1u)) >> 16;
  return (unsigned short)r;
}

__global__ void zero_kernel(float* p) { p[0] = 0.f; }

// ---------------- embedding ----------------
__global__ __launch_bounds__(128) void embed_kernel(const int* __restrict__ idx,
    const float* __restrict__ tok, const float* __restrict__ pos, float* __restrict__ x) {
  int bt = blockIdx.x;
  int t  = bt & (T_ - 1);
  int id = idx[bt];
  if (id < 0) id = 0; if (id > V_ - 1) id = V_ - 1;
  int d  = threadIdx.x * 4;
  float4 tv = *(const float4*)(tok + (size_t)id * D_ + d);
  float4 pv = *(const float4*)(pos + (size_t)t  * D_ + d);
  float4 o = {tv.x + pv.x, tv.y + pv.y, tv.z + pv.z, tv.w + pv.w};
  *(float4*)(x + (size_t)bt * D_ + d) = o;
}

// ---------------- tiled transpose + f32->bf16: dst[C][R] = src[R][C] ----------------
__global__ __launch_bounds__(256) void transpose_cvt(const float* __restrict__ src,
    unsigned short* __restrict__ dst, int R, int C, long sstride, long dstride,
    int zper, long zouter) {
  __shared__ float t[32][33];
  const float* s = src + (size_t)blockIdx.z * sstride;
  unsigned short* d = dst + (size_t)(blockIdx.z / zper) * zouter
                          + (size_t)(blockIdx.z % zper) * dstride;
  int r0 = blockIdx.y * 32, c0 = blockIdx.x * 32;
  int tr = threadIdx.x >> 5, tc = threadIdx.x & 31;
#pragma unroll
  for (int i = 0; i < 4; ++i)
    t[tr + i * 8][tc] = s[(size_t)(r0 + tr + i * 8) * C + c0 + tc];
  __syncthreads();
#pragma unroll
  for (int i = 0; i < 4; ++i)
    d[(size_t)(c0 + tr + i * 8) * R + r0 + tc] = f2b(t[tc][tr + i * 8]);
}

// ---------------- layernorm: one wave per row, fully vectorized ----------------
template<bool BF16OUT>
__global__ __launch_bounds__(256) void ln_kernel(const float* __restrict__ x,
    const float* __restrict__ s, const float* __restrict__ b, void* __restrict__ outv) {
  int wave = threadIdx.x >> 6;
  int lane = threadIdx.x & 63;
  int r = blockIdx.x * 4 + wave;
  const float* xr = x + (size_t)r * D_ + lane * 8;
  float4 va = *(const float4*)(xr);
  float4 vb = *(const float4*)(xr + 4);
  float vals[8] = {va.x, va.y, va.z, va.w, vb.x, vb.y, vb.z, vb.w};
  float sum = 0.f;
#pragma unroll
  for (int j = 0; j < 8; ++j) sum += vals[j];
#pragma unroll
  for (int o = 32; o > 0; o >>= 1) sum += __shfl_xor(sum, o, 64);
  float mean = sum * (1.f / D_);
  float vs = 0.f;
#pragma unroll
  for (int j = 0; j < 8; ++j) { float d = vals[j] - mean; vs += d * d; }
#pragma unroll
  for (int o = 32; o > 0; o >>= 1) vs += __shfl_xor(vs, o, 64);
  float rstd = rsqrtf(vs * (1.f / D_) + 1e-5f);
  float4 sa = *(const float4*)(s + lane * 8);
  float4 sb = *(const float4*)(s + lane * 8 + 4);
  float4 ba = *(const float4*)(b + lane * 8);
  float4 bb = *(const float4*)(b + lane * 8 + 4);
  float sc[8] = {sa.x, sa.y, sa.z, sa.w, sb.x, sb.y, sb.z, sb.w};
  float bc[8] = {ba.x, ba.y, ba.z, ba.w, bb.x, bb.y, bb.z, bb.w};
  float v[8];
#pragma unroll
  for (int j = 0; j < 8; ++j) v[j] = (vals[j] - mean) * rstd * sc[j] + bc[j];
  if (BF16OUT) {
    uint4 pk;
    pk.x = (unsigned)f2b(v[0]) | ((unsigned)f2b(v[1]) << 16);
    pk.y = (unsigned)f2b(v[2]) | ((unsigned)f2b(v[3]) << 16);
    pk.z = (unsigned)f2b(v[4]) | ((unsigned)f2b(v[5]) << 16);
    pk.w = (unsigned)f2b(v[6]) | ((unsigned)f2b(v[7]) << 16);
    *(uint4*)((unsigned short*)outv + (size_t)r * D_ + lane * 8) = pk;
  } else {
    float* op = (float*)outv + (size_t)r * D_ + lane * 8;
    *(float4*)(op)     = make_float4(v[0], v[1], v[2], v[3]);
    *(float4*)(op + 4) = make_float4(v[4], v[5], v[6], v[7]);
  }
}

// ---------------- bf16 MFMA GEMM: C[M,N] (+)= A[M,K] @ Bt[N,K]^T ----------------
// R12: exact restore of the best-measured configuration (R8, 1834.5us; R7
// 1831.8us — noise-equal). 2-phase double-buffered LDS, gload_lds width=16,
// XCD-bijective swizzle, 128x128 for QKV/FF1, 64x128 for proj/FF2.
// Five structural variants all measured neutral-to-worse at these shapes:
//   R5 depth-2 counted-vmcnt (+20us), R6 64x64 tiles (+126us), R7 256x256
//   8-phase (null), R9 split-K atomic combine (+600us, HBM-RMW-bound),
//   R11 in-block split-K via LDS (+150us). The simple 2-phase x blocks/CU
//   config is the robust local optimum for this dispatch-serialized workload.
// OUTMODE: 0 = f32 [M][ldc], 1 = bf16 [M][ldc],
//          3 = fused QKV: cols 0..1023 -> bf16 [M][QKS], cols 1024..1535 -> Vt
#define BK 32
template<bool ACC, bool RELU, bool BIAS, int OUTMODE, int MT, int NT>
__global__ __launch_bounds__(256) void mfma_gemm(
    const unsigned short* __restrict__ A,
    const unsigned short* __restrict__ Bt,
    const float* __restrict__ bias,
    void* __restrict__ Cv, void* __restrict__ Cv2,
    int K, int ldc) {
  constexpr int NI = (MT == 128) ? 4 : (NT == 128 ? 2 : 1);
  constexpr int WN = (MT == 128) ? 64 : (NT == 128 ? 32 : 16);
  __shared__ unsigned short Al[2][MT * BK];
  __shared__ unsigned short Bl[2][NT * BK];
  const int nwg = gridDim.x * gridDim.y;
  const int flat = blockIdx.x + gridDim.x * blockIdx.y;
  const int swz = (flat & 7) * (nwg >> 3) + (flat >> 3);
  const int bx = swz / gridDim.y;
  const int by = swz % gridDim.y;
  const int m0 = bx * MT, n0 = by * NT;
  const int tid = threadIdx.x;
  const int lane = tid & 63, wave = tid >> 6;
  const int wy = (MT == 128) ? (wave >> 1) : 0;
  const int wx = (MT == 128) ? (wave & 1) : wave;
  const int l15 = lane & 15, quad = lane >> 4;

  const int sbase = wave * 1024;
  const int soff  = sbase + lane * 16;
  const int r0 = soff >> 6, c0e = (soff & 63) >> 1;
  const int r1 = r0 + 64;
  const int ls = sbase >> 1;
  const unsigned short* gA0 = A  + (size_t)(m0 + r0) * K + c0e;
  const unsigned short* gA1 = A  + (size_t)(m0 + r1) * K + c0e;  // MT==128 only
  const unsigned short* gB0 = Bt + (size_t)(n0 + r0) * K + c0e;
  const unsigned short* gB1 = Bt + (size_t)(n0 + r1) * K + c0e;  // NT==128 only

  auto stage = [&](int buf, int k0) {
    gload16(gA0 + k0, &Al[buf][ls]);
    if constexpr (MT == 128) gload16(gA1 + k0, &Al[buf][ls + 2048]);
    gload16(gB0 + k0, &Bl[buf][ls]);
    if constexpr (NT == 128) gload16(gB1 + k0, &Bl[buf][ls + 2048]);
  };

  f32x4 acc[4][NI];
  const f32x4 z4 = {0.f, 0.f, 0.f, 0.f};
#pragma unroll
  for (int mi = 0; mi < 4; ++mi)
#pragma unroll
    for (int ni = 0; ni < NI; ++ni) acc[mi][ni] = z4;

  stage(0, 0);
  __syncthreads();

  const int nsteps = K / BK;
  int cur = 0;
  for (int s = 0; s < nsteps; ++s) {
    if (s + 1 < nsteps) stage(cur ^ 1, (s + 1) * BK);
    bf16x8 af[4], bfr[NI];
#pragma unroll
    for (int mi = 0; mi < 4; ++mi)
      af[mi] = *(const bf16x8*)(&Al[cur][(wy * 64 + mi * 16 + l15) * BK + quad * 8]);
#pragma unroll
    for (int ni = 0; ni < NI; ++ni)
      bfr[ni] = *(const bf16x8*)(&Bl[cur][(wx * WN + ni * 16 + l15) * BK + quad * 8]);
#pragma unroll
    for (int mi = 0; mi < 4; ++mi)
#pragma unroll
      for (int ni = 0; ni < NI; ++ni)
        acc[mi][ni] = __builtin_amdgcn_mfma_f32_16x16x32_bf16(af[mi], bfr[ni], acc[mi][ni], 0, 0, 0);
    if (s + 1 < nsteps) {
      __syncthreads();
      cur ^= 1;
    }
  }

#pragma unroll
  for (int mi = 0; mi < 4; ++mi) {
    int row0 = m0 + wy * 64 + mi * 16 + quad * 4;
#pragma unroll
    for (int ni = 0; ni < NI; ++ni) {
      int col = n0 + wx * WN + ni * 16 + l15;
      float bb = BIAS ? bias[col] : 0.f;
#pragma unroll
      for (int r = 0; r < 4; ++r) {
        float v = acc[mi][ni][r] + bb;
        if (RELU) v = fmaxf(v, 0.f);
        int row = row0 + r;
        if (OUTMODE == 3) {
          if (col < 1024) {
            ((unsigned short*)Cv)[(size_t)row * QKS + col] = f2b(v);
          } else {
            int vcol = col - 1024;
            int b = row >> 10, t = row & (T_ - 1);
            int h = vcol >> 6, hs = vcol & 63;
            ((unsigned short*)Cv2)[((size_t)((b * H_ + h) * HS_ + hs)) * T_ + t] = f2b(v);
          }
        } else {
          size_t off = (size_t)row * ldc + col;
          if (ACC) v += ((const float*)Cv)[off];
          if (OUTMODE == 1) ((unsigned short*)Cv)[off] = f2b(v);
          else              ((float*)Cv)[off] = v;
        }
      }
    }
  }
}

// ---------------- MFMA flash attention, no-max softmax ----------------
// Fold-paired (17 uniform iterations/block). P conversion via paired
// v_cvt_pk_bf16_f32; denominator accumulates unrounded f32 p.
#define PSTR 72
__global__ __launch_bounds__(256) void attn_mfma(const unsigned short* __restrict__ q,
    const unsigned short* __restrict__ k, const unsigned short* __restrict__ vt,
    unsigned short* __restrict__ o) {
  __shared__ unsigned short Pbuf[2][64 * PSTR];
  __shared__ float Lsum[4][64];
  const int bh = blockIdx.y;
  const int b = bh >> 3, hh = bh & 7;
  const int tid = threadIdx.x;
  const int lane = tid & 63, w = tid >> 6;
  const int l15 = lane & 15, quad = lane >> 4;
  const float CEXP = 0.044194173824159216f * 1.4426950408889634f;  // scale*log2(e)

  const unsigned short* kbase = k  + (size_t)(b * T_ + w * 16 + l15) * QKS + hh * HS_ + quad * 8;
  const unsigned short* vbase = vt + ((size_t)(bh * HS_ + w * 16 + l15)) * T_ + quad * 8;
  const int gc = w * 16 + l15;
  const f32x4 z4 = {0.f, 0.f, 0.f, 0.f};

  for (int pass = 0; pass < 2; ++pass) {
    const int qt = pass ? (int)blockIdx.x : (T_ / 64 - 1 - (int)blockIdx.x);

    bf16x8 qf[4][2];
#pragma unroll
    for (int mi = 0; mi < 4; ++mi)
#pragma unroll
      for (int c = 0; c < 2; ++c)
        qf[mi][c] = *(const bf16x8*)(q + (size_t)(b * T_ + qt * 64 + mi * 16 + l15) * QKS
                                       + hh * HS_ + c * 32 + quad * 8);

    f32x4 oacc[4];
    float psum[4][4];
#pragma unroll
    for (int mi = 0; mi < 4; ++mi) {
      oacc[mi] = z4;
#pragma unroll
      for (int r = 0; r < 4; ++r) psum[mi][r] = 0.f;
    }

    bf16x8 kf[2], vf[2];
#pragma unroll
    for (int c = 0; c < 2; ++c) {
      kf[c] = *(const bf16x8*)(kbase + c * 32);
      vf[c] = *(const bf16x8*)(vbase + c * 32);
    }

    for (int kt = 0; kt <= qt; ++kt) {
      const int ktn = (kt < qt) ? kt + 1 : qt;
      bf16x8 kfn[2], vfn[2];
#pragma unroll
      for (int c = 0; c < 2; ++c) {
        kfn[c] = *(const bf16x8*)(kbase + (size_t)ktn * 64 * QKS + c * 32);
        vfn[c] = *(const bf16x8*)(vbase + ktn * 64 + c * 32);
      }

      f32x4 s[4];
#pragma unroll
      for (int mi = 0; mi < 4; ++mi) s[mi] = z4;
      __builtin_amdgcn_s_setprio(1);
#pragma unroll
      for (int c = 0; c < 2; ++c)
#pragma unroll
        for (int mi = 0; mi < 4; ++mi)
          s[mi] = __builtin_amdgcn_mfma_f32_16x16x32_bf16(qf[mi][c], kf[c], s[mi], 0, 0, 0);
      __builtin_amdgcn_s_setprio(0);

      unsigned short* pb = Pbuf[kt & 1];
      const bool diag = (kt == qt);
#pragma unroll
      for (int mi = 0; mi < 4; ++mi) {
        const int row0 = mi * 16 + quad * 4;
        float pv_[4];
#pragma unroll
        for (int r = 0; r < 4; ++r) {
          float p = exp2f(s[mi][r] * CEXP);
          if (diag && gc > row0 + r) p = 0.f;
          psum[mi][r] += p;
          pv_[r] = p;
        }
        unsigned pk01, pk23;
        asm("v_cvt_pk_bf16_f32 %0, %1, %2" : "=v"(pk01) : "v"(pv_[0]), "v"(pv_[1]));
        asm("v_cvt_pk_bf16_f32 %0, %1, %2" : "=v"(pk23) : "v"(pv_[2]), "v"(pv_[3]));
        const int base = row0 * PSTR + gc;
        pb[base]            = (unsigned short)(pk01 & 0xFFFFu);
        pb[base + PSTR]     = (unsigned short)(pk01 >> 16);
        pb[base + 2 * PSTR] = (unsigned short)(pk23 & 0xFFFFu);
        pb[base + 3 * PSTR] = (unsigned short)(pk23 >> 16);
      }
      __syncthreads();
      __builtin_amdgcn_s_setprio(1);
#pragma unroll
      for (int c = 0; c < 2; ++c) {
#pragma unroll
        for (int mi = 0; mi < 4; ++mi) {
          bf16x8 pf = *(const bf16x8*)(&pb[(mi * 16 + l15) * PSTR + c * 32 + quad * 8]);
          oacc[mi] = __builtin_amdgcn_mfma_f32_16x16x32_bf16(pf, vf[c], oacc[mi], 0, 0, 0);
        }
      }
      __builtin_amdgcn_s_setprio(0);
#pragma unroll
      for (int c = 0; c < 2; ++c) { kf[c] = kfn[c]; vf[c] = vfn[c]; }
    }

#pragma unroll
    for (int mi = 0; mi < 4; ++mi)
#pragma unroll
      for (int r = 0; r < 4; ++r) {
#pragma unroll
        for (int off = 1; off < 16; off <<= 1)
          psum[mi][r] += __shfl_xor(psum[mi][r], off, 64);
      }
    if (l15 == 0) {
#pragma unroll
      for (int mi = 0; mi < 4; ++mi)
#pragma unroll
        for (int r = 0; r < 4; ++r)
          Lsum[w][mi * 16 + quad * 4 + r] = psum[mi][r];
    }
    __syncthreads();
#pragma unroll
    for (int mi = 0; mi < 4; ++mi)
#pragma unroll
      for (int r = 0; r < 4; ++r) {
        int row = mi * 16 + quad * 4 + r;
        float inv = 1.f / (Lsum[0][row] + Lsum[1][row] + Lsum[2][row] + Lsum[3][row]);
        o[(size_t)(b * T_ + qt * 64 + row) * D_ + hh * HS_ + w * 16 + l15] =
            f2b(oacc[mi][r] * inv);
      }
  }
}

// ---------------- f32 tiled GEMM (logits only) ----------------
__global__ __launch_bounds__(256) void gemm_f32_kernel(const float* __restrict__ A, int lda,
    const float* __restrict__ Bw, int ldb, const float* __restrict__ bias,
    float* __restrict__ C, int ldc, int K, int N) {
  __shared__ float As[16][64];
  __shared__ float Bs[16][64];
  int n0 = blockIdx.y * 64;
  int nv = N - n0; if (nv > 64) nv = 64;
  int m0 = blockIdx.x * 64;
  const int tid = threadIdx.x;
  const int tx = tid & 15, ty = tid >> 4;
  const int amm = tid >> 2;
  const int akk = (tid & 3) * 4;
  const int bkk = tid >> 4;
  const int bnn = (tid & 15) * 4;
  float acc[4][4] = {};
  for (int k0 = 0; k0 < K; k0 += 16) {
    float4 av = *(const float4*)(A + (size_t)(m0 + amm) * lda + k0 + akk);
    As[akk + 0][amm] = av.x; As[akk + 1][amm] = av.y;
    As[akk + 2][amm] = av.z; As[akk + 3][amm] = av.w;
    if (bnn < nv) {
      float4 bv = *(const float4*)(Bw + (size_t)(k0 + bkk) * ldb + n0 + bnn);
      Bs[bkk][bnn + 0] = bv.x; Bs[bkk][bnn + 1] = bv.y;
      Bs[bkk][bnn + 2] = bv.z; Bs[bkk][bnn + 3] = bv.w;
    } else {
      Bs[bkk][bnn + 0] = 0.f; Bs[bkk][bnn + 1] = 0.f;
      Bs[bkk][bnn + 2] = 0.f; Bs[bkk][bnn + 3] = 0.f;
    }
    __syncthreads();
#pragma unroll
    for (int kk = 0; kk < 16; ++kk) {
      float4 a4 = *(const float4*)(&As[kk][ty * 4]);
      float4 b4 = *(const float4*)(&Bs[kk][tx * 4]);
      float aa[4] = {a4.x, a4.y, a4.z, a4.w};
      float bb[4] = {b4.x, b4.y, b4.z, b4.w};
#pragma unroll
      for (int i = 0; i < 4; ++i)
#pragma unroll
        for (int j = 0; j < 4; ++j)
          acc[i][j] = fmaf(aa[i], bb[j], acc[i][j]);
    }
    __syncthreads();
  }
  if (tx * 4 < nv) {
#pragma unroll
    for (int i = 0; i < 4; ++i) {
      float* cp = C + (size_t)(m0 + ty * 4 + i) * ldc + n0 + tx * 4;
      float4 st = {acc[i][0] + bias[n0 + tx * 4 + 0], acc[i][1] + bias[n0 + tx * 4 + 1],
                   acc[i][2] + bias[n0 + tx * 4 + 2], acc[i][3] + bias[n0 + tx * 4 + 3]};
      *(float4*)cp = st;
    }
  }
}

// ---------------- loss ----------------
__global__ __launch_bounds__(256) void loss_kernel(const float* __restrict__ logits,
    const int* __restrict__ targets, float* __restrict__ loss_acc) {
  __shared__ float wsum[4];
  int wave = threadIdx.x >> 6, lane = threadIdx.x & 63;
  float local = 0.f;
  for (int r = blockIdx.x * 4 + wave; r < BT_; r += gridDim.x * 4) {
    const float* lr = logits + (size_t)r * V_;
    float v0 = lr[lane];
    float v1 = (lane < 32) ? lr[64 + lane] : -INFINITY;
    float mx = fmaxf(v0, v1);
#pragma unroll
    for (int o = 32; o > 0; o >>= 1) mx = fmaxf(mx, __shfl_xor(mx, o, 64));
    float se = expf(v0 - mx) + ((lane < 32) ? expf(v1 - mx) : 0.f);
#pragma unroll
    for (int o = 32; o > 0; o >>= 1) se += __shfl_xor(se, o, 64);
    if (lane == 0) {
      int tg = targets[r];
      if (tg < 0) tg = 0; if (tg > V_ - 1) tg = V_ - 1;
      local += (mx + logf(se)) - lr[tg];
    }
  }
  if (lane == 0) wsum[wave] = local;
  __syncthreads();
  if (threadIdx.x == 0)
    atomicAdd(loss_acc, wsum[0] + wsum[1] + wsum[2] + wsum[3]);
}

__global__ void loss_finalize_kernel(const float* __restrict__ acc, float* __restrict__ out) {
  out[(size_t)BT_ * V_] = acc[0] * (1.f / BT_);
}

// ---------------- host ----------------
static void* g_ws_fallback = nullptr;

extern "C" void kernel_launch(void* const* d_in, const int* in_sizes, int n_in,
                              void* d_out, int out_size, void* d_ws, size_t ws_size,
                              hipStream_t stream) {
  const int*   idx     = (const int*)d_in[0];
  const int*   targets = (const int*)d_in[1];
  const float* tok  = (const float*)d_in[2];
  const float* pos  = (const float*)d_in[3];
  const float* Wq   = (const float*)d_in[4];
  const float* Wk   = (const float*)d_in[5];
  const float* Wv   = (const float*)d_in[6];
  const float* Wp   = (const float*)d_in[7];
  const float* bp   = (const float*)d_in[8];
  const float* W1   = (const float*)d_in[9];
  const float* b1   = (const float*)d_in[10];
  const float* W2   = (const float*)d_in[11];
  const float* b2   = (const float*)d_in[12];
  const float* l1s  = (const float*)d_in[13];
  const float* l1b  = (const float*)d_in[14];
  const float* l2s  = (const float*)d_in[15];
  const float* l2b  = (const float*)d_in[16];
  const float* lfs  = (const float*)d_in[17];
  const float* lfb  = (const float*)d_in[18];
  const float* Wout = (const float*)d_in[19];
  const float* bout = (const float*)d_in[20];
  float* out = (float*)d_out;   // f32 logits + f32 loss scalar

  const size_t n_x  = (size_t)BT_ * D_;
  const size_t n_wT = 9437184;   // transposed bf16 weights (f32-equiv)
  const size_t need_floats = n_x + n_x + n_x / 2 + n_x / 2 + n_x / 2 +
                             (size_t)BT_ * FF_ / 2 + n_wT + 256;
  const size_t need_bytes  = need_floats * sizeof(float);

  float* ws;
  if (ws_size >= need_bytes) {
    ws = (float*)d_ws;
  } else {
    if (!g_ws_fallback) (void)hipMalloc(&g_ws_fallback, need_bytes);
    ws = (float*)g_ws_fallback;
  }

  size_t off = 0;
  float* x  = ws + off; off += n_x;
  float* qf32 = ws + off; off += n_x;          // Q|K interleaved bf16 [BT][1024]; reused f32 final-LN
  unsigned short* qkb = (unsigned short*)qf32;
  unsigned short* spare = (unsigned short*)(ws + off); off += n_x / 2;
  unsigned short* vtb = (unsigned short*)(ws + off); off += n_x / 2;
  unsigned short* hb  = (unsigned short*)(ws + off); off += n_x / 2;
  unsigned short* ffb = (unsigned short*)(ws + off); off += (size_t)BT_ * FF_ / 2;
  unsigned short* wqkvT = (unsigned short*)(ws + off);   // per-layer [1536][512]
  unsigned short* wpT = wqkvT + (size_t)L_ * 3 * D_ * D_;
  unsigned short* w1T = wpT + (size_t)L_ * D_ * D_;
  unsigned short* w2T = w1T + (size_t)L_ * D_ * FF_;
  off += n_wT;
  float* lacc = ws + off;
  (void)spare;

  const long DD = (long)D_ * D_;          // 262144
  const long L3DD = 3 * DD;               // per-layer combined QKV stride

  zero_kernel<<<1, 1, 0, stream>>>(lacc);
  embed_kernel<<<BT_, 128, 0, stream>>>(idx, tok, pos, x);

  // combined QKV weight transpose: layer l rows [0,512)=Q, [512,1024)=K, [1024,1536)=V
  transpose_cvt<<<dim3(2, 16, 48), 256, 0, stream>>>(Wq, wqkvT,            512, 64, 32768, 32768, 8, L3DD);
  transpose_cvt<<<dim3(2, 16, 48), 256, 0, stream>>>(Wk, wqkvT + DD,       512, 64, 32768, 32768, 8, L3DD);
  transpose_cvt<<<dim3(2, 16, 48), 256, 0, stream>>>(Wv, wqkvT + 2 * DD,   512, 64, 32768, 32768, 8, L3DD);
  transpose_cvt<<<dim3(16, 16, 6), 256, 0, stream>>>(Wp, wpT, 512, 512, 262144, 0, 1, 262144);
  transpose_cvt<<<dim3(64, 16, 6), 256, 0, stream>>>(W1, w1T, 512, 2048, 1048576, 0, 1, 1048576);
  transpose_cvt<<<dim3(16, 64, 6), 256, 0, stream>>>(W2, w2T, 2048, 512, 1048576, 0, 1, 1048576);

  const dim3 gQKV(BT_ / 128, 12);         // 768 blocks, 128x128
  const dim3 gF(BT_ / 128, FF_ / 128);    // 1024 blocks, 128x128
  const dim3 gD64(BT_ / 64, D_ / 128);    // 512 blocks, 64x128 (proj/FF2)

  for (int l = 0; l < L_; ++l) {
    ln_kernel<true><<<BT_ / 4, 256, 0, stream>>>(x, l1s + (size_t)l * D_, l1b + (size_t)l * D_, hb);
    mfma_gemm<false, false, false, 3, 128, 128><<<gQKV, 256, 0, stream>>>(
        hb, wqkvT + (size_t)l * L3DD, nullptr, qkb, vtb, D_, 0);
    attn_mfma<<<dim3(T_ / 128, B_ * H_), 256, 0, stream>>>(qkb, qkb + 512, vtb, hb);
    mfma_gemm<true, false, true, 0, 64, 128><<<gD64, 256, 0, stream>>>(
        hb, wpT + (size_t)l * DD, bp + (size_t)l * D_, x, nullptr, D_, D_);
    ln_kernel<true><<<BT_ / 4, 256, 0, stream>>>(x, l2s + (size_t)l * D_, l2b + (size_t)l * D_, hb);
    mfma_gemm<false, true, true, 1, 128, 128><<<gF, 256, 0, stream>>>(
        hb, w1T + (size_t)l * D_ * FF_, b1 + (size_t)l * FF_, ffb, nullptr, D_, FF_);
    mfma_gemm<true, false, true, 0, 64, 128><<<gD64, 256, 0, stream>>>(
        ffb, w2T + (size_t)l * FF_ * D_, b2 + (size_t)l * D_, x, nullptr, FF_, D_);
  }

  ln_kernel<false><<<BT_ / 4, 256, 0, stream>>>(x, lfs, lfb, qf32);
  gemm_f32_kernel<<<dim3(BT_ / 64, 2), 256, 0, stream>>>(
      qf32, D_, Wout, V_, bout, out, V_, D_, V_);
  loss_kernel<<<1024, 256, 0, stream>>>(out, targets, lacc);
  loss_finalize_kernel<<<1, 1, 0, stream>>>(lacc, out);
}

// Round 13
// 1768.452 us; speedup vs baseline: 1.1230x; 1.0350x over previous
//
#include <hip/hip_runtime.h>

#define B_  16
#define T_  1024
#define D_  512
#define H_  8
#define L_  6
#define V_  96
#define HS_ 64
#define FF_ 2048
#define BT_ (B_*T_)
#define QKS 1024   // row stride (shorts) of the fused Q|K activation buffer

typedef __attribute__((ext_vector_type(8))) short bf16x8;
typedef __attribute__((ext_vector_type(4))) float f32x4;

typedef __attribute__((address_space(3))) unsigned int lds_u32_t;
typedef const __attribute__((address_space(1))) unsigned int glb_u32_t;

__device__ __forceinline__ void gload16(const unsigned short* g, unsigned short* l) {
  __builtin_amdgcn_global_load_lds((glb_u32_t*)g, (lds_u32_t*)l, 16, 0, 0);
}

__device__ __forceinline__ unsigned short f2b(float f) {
  unsigned u = __float_as_uint(f);
  unsigned r = (u + 0x7FFFu + ((u >> 16) & 1u)) >> 16;
  return (unsigned short)r;
}

__global__ void zero_kernel(float* p) { p[0] = 0.f; }

// ---------------- embedding ----------------
__global__ __launch_bounds__(128) void embed_kernel(const int* __restrict__ idx,
    const float* __restrict__ tok, const float* __restrict__ pos, float* __restrict__ x) {
  int bt = blockIdx.x;
  int t  = bt & (T_ - 1);
  int id = idx[bt];
  if (id < 0) id = 0; if (id > V_ - 1) id = V_ - 1;
  int d  = threadIdx.x * 4;
  float4 tv = *(const float4*)(tok + (size_t)id * D_ + d);
  float4 pv = *(const float4*)(pos + (size_t)t  * D_ + d);
  float4 o = {tv.x + pv.x, tv.y + pv.y, tv.z + pv.z, tv.w + pv.w};
  *(float4*)(x + (size_t)bt * D_ + d) = o;
}

// ---------------- tiled transpose + f32->bf16: dst[C][R] = src[R][C] ----------------
__global__ __launch_bounds__(256) void transpose_cvt(const float* __restrict__ src,
    unsigned short* __restrict__ dst, int R, int C, long sstride, long dstride,
    int zper, long zouter) {
  __shared__ float t[32][33];
  const float* s = src + (size_t)blockIdx.z * sstride;
  unsigned short* d = dst + (size_t)(blockIdx.z / zper) * zouter
                          + (size_t)(blockIdx.z % zper) * dstride;
  int r0 = blockIdx.y * 32, c0 = blockIdx.x * 32;
  int tr = threadIdx.x >> 5, tc = threadIdx.x & 31;
#pragma unroll
  for (int i = 0; i < 4; ++i)
    t[tr + i * 8][tc] = s[(size_t)(r0 + tr + i * 8) * C + c0 + tc];
  __syncthreads();
#pragma unroll
  for (int i = 0; i < 4; ++i)
    d[(size_t)(c0 + tr + i * 8) * R + r0 + tc] = f2b(t[tc][tr + i * 8]);
}

// ---------------- bf16 V transpose: vtb[b*512+c][t] = vb[b*T+t][c] ----------------
// R13: QKV writes V coalesced ([bt][512], lane-contiguous) instead of the 2B
// stride-2KB scatter (R10 measured ~2x write amplification: QKV WRITE 50MB vs
// 24MB ideal). This kernel does the [T][512]->[512][T] per-batch transpose with
// coalesced 64B reads/writes through LDS.
__global__ __launch_bounds__(256) void vtrans_kernel(const unsigned short* __restrict__ src,
    unsigned short* __restrict__ dst) {
  __shared__ unsigned short t[32][34];
  const int b = blockIdx.z;
  const unsigned short* s = src + (size_t)b * T_ * 512;
  unsigned short* d = dst + (size_t)b * 512 * T_;
  int r0 = blockIdx.y * 32, c0 = blockIdx.x * 32;
  int tr = threadIdx.x >> 5, tc = threadIdx.x & 31;
#pragma unroll
  for (int i = 0; i < 4; ++i)
    t[tr + i * 8][tc] = s[(size_t)(r0 + tr + i * 8) * 512 + c0 + tc];
  __syncthreads();
#pragma unroll
  for (int i = 0; i < 4; ++i)
    d[(size_t)(c0 + tr + i * 8) * T_ + r0 + tc] = t[tc][tr + i * 8];
}

// ---------------- layernorm: one wave per row, fully vectorized ----------------
template<bool BF16OUT>
__global__ __launch_bounds__(256) void ln_kernel(const float* __restrict__ x,
    const float* __restrict__ s, const float* __restrict__ b, void* __restrict__ outv) {
  int wave = threadIdx.x >> 6;
  int lane = threadIdx.x & 63;
  int r = blockIdx.x * 4 + wave;
  const float* xr = x + (size_t)r * D_ + lane * 8;
  float4 va = *(const float4*)(xr);
  float4 vb = *(const float4*)(xr + 4);
  float vals[8] = {va.x, va.y, va.z, va.w, vb.x, vb.y, vb.z, vb.w};
  float sum = 0.f;
#pragma unroll
  for (int j = 0; j < 8; ++j) sum += vals[j];
#pragma unroll
  for (int o = 32; o > 0; o >>= 1) sum += __shfl_xor(sum, o, 64);
  float mean = sum * (1.f / D_);
  float vs = 0.f;
#pragma unroll
  for (int j = 0; j < 8; ++j) { float d = vals[j] - mean; vs += d * d; }
#pragma unroll
  for (int o = 32; o > 0; o >>= 1) vs += __shfl_xor(vs, o, 64);
  float rstd = rsqrtf(vs * (1.f / D_) + 1e-5f);
  float4 sa = *(const float4*)(s + lane * 8);
  float4 sb = *(const float4*)(s + lane * 8 + 4);
  float4 ba = *(const float4*)(b + lane * 8);
  float4 bb = *(const float4*)(b + lane * 8 + 4);
  float sc[8] = {sa.x, sa.y, sa.z, sa.w, sb.x, sb.y, sb.z, sb.w};
  float bc[8] = {ba.x, ba.y, ba.z, ba.w, bb.x, bb.y, bb.z, bb.w};
  float v[8];
#pragma unroll
  for (int j = 0; j < 8; ++j) v[j] = (vals[j] - mean) * rstd * sc[j] + bc[j];
  if (BF16OUT) {
    uint4 pk;
    pk.x = (unsigned)f2b(v[0]) | ((unsigned)f2b(v[1]) << 16);
    pk.y = (unsigned)f2b(v[2]) | ((unsigned)f2b(v[3]) << 16);
    pk.z = (unsigned)f2b(v[4]) | ((unsigned)f2b(v[5]) << 16);
    pk.w = (unsigned)f2b(v[6]) | ((unsigned)f2b(v[7]) << 16);
    *(uint4*)((unsigned short*)outv + (size_t)r * D_ + lane * 8) = pk;
  } else {
    float* op = (float*)outv + (size_t)r * D_ + lane * 8;
    *(float4*)(op)     = make_float4(v[0], v[1], v[2], v[3]);
    *(float4*)(op + 4) = make_float4(v[4], v[5], v[6], v[7]);
  }
}

// ---------------- bf16 MFMA GEMM: C[M,N] (+)= A[M,K] @ Bt[N,K]^T ----------------
// Best-measured config (R12 = 1830us): 2-phase double-buffered LDS, gload_lds
// width=16, XCD-bijective swizzle, 128x128 for QKV/FF1, 64x128 for proj/FF2.
// R13 change: OUTMODE 3 writes V COALESCED to vb [M][512] (was transposed 2B
// scatter at stride T -> ~2x write amplification); a separate vtrans kernel
// produces vtb for attn.
// OUTMODE: 0 = f32 [M][ldc], 1 = bf16 [M][ldc],
//          3 = fused QKV: cols 0..1023 -> bf16 [M][QKS] (Cv),
//              cols 1024..1535 -> bf16 vb[M][512] (Cv2, coalesced)
#define BK 32
template<bool ACC, bool RELU, bool BIAS, int OUTMODE, int MT, int NT>
__global__ __launch_bounds__(256) void mfma_gemm(
    const unsigned short* __restrict__ A,
    const unsigned short* __restrict__ Bt,
    const float* __restrict__ bias,
    void* __restrict__ Cv, void* __restrict__ Cv2,
    int K, int ldc) {
  constexpr int NI = (MT == 128) ? 4 : (NT == 128 ? 2 : 1);
  constexpr int WN = (MT == 128) ? 64 : (NT == 128 ? 32 : 16);
  __shared__ unsigned short Al[2][MT * BK];
  __shared__ unsigned short Bl[2][NT * BK];
  const int nwg = gridDim.x * gridDim.y;
  const int flat = blockIdx.x + gridDim.x * blockIdx.y;
  const int swz = (flat & 7) * (nwg >> 3) + (flat >> 3);
  const int bx = swz / gridDim.y;
  const int by = swz % gridDim.y;
  const int m0 = bx * MT, n0 = by * NT;
  const int tid = threadIdx.x;
  const int lane = tid & 63, wave = tid >> 6;
  const int wy = (MT == 128) ? (wave >> 1) : 0;
  const int wx = (MT == 128) ? (wave & 1) : wave;
  const int l15 = lane & 15, quad = lane >> 4;

  const int sbase = wave * 1024;
  const int soff  = sbase + lane * 16;
  const int r0 = soff >> 6, c0e = (soff & 63) >> 1;
  const int r1 = r0 + 64;
  const int ls = sbase >> 1;
  const unsigned short* gA0 = A  + (size_t)(m0 + r0) * K + c0e;
  const unsigned short* gA1 = A  + (size_t)(m0 + r1) * K + c0e;  // MT==128 only
  const unsigned short* gB0 = Bt + (size_t)(n0 + r0) * K + c0e;
  const unsigned short* gB1 = Bt + (size_t)(n0 + r1) * K + c0e;  // NT==128 only

  auto stage = [&](int buf, int k0) {
    gload16(gA0 + k0, &Al[buf][ls]);
    if constexpr (MT == 128) gload16(gA1 + k0, &Al[buf][ls + 2048]);
    gload16(gB0 + k0, &Bl[buf][ls]);
    if constexpr (NT == 128) gload16(gB1 + k0, &Bl[buf][ls + 2048]);
  };

  f32x4 acc[4][NI];
  const f32x4 z4 = {0.f, 0.f, 0.f, 0.f};
#pragma unroll
  for (int mi = 0; mi < 4; ++mi)
#pragma unroll
    for (int ni = 0; ni < NI; ++ni) acc[mi][ni] = z4;

  stage(0, 0);
  __syncthreads();

  const int nsteps = K / BK;
  int cur = 0;
  for (int s = 0; s < nsteps; ++s) {
    if (s + 1 < nsteps) stage(cur ^ 1, (s + 1) * BK);
    bf16x8 af[4], bfr[NI];
#pragma unroll
    for (int mi = 0; mi < 4; ++mi)
      af[mi] = *(const bf16x8*)(&Al[cur][(wy * 64 + mi * 16 + l15) * BK + quad * 8]);
#pragma unroll
    for (int ni = 0; ni < NI; ++ni)
      bfr[ni] = *(const bf16x8*)(&Bl[cur][(wx * WN + ni * 16 + l15) * BK + quad * 8]);
#pragma unroll
    for (int mi = 0; mi < 4; ++mi)
#pragma unroll
      for (int ni = 0; ni < NI; ++ni)
        acc[mi][ni] = __builtin_amdgcn_mfma_f32_16x16x32_bf16(af[mi], bfr[ni], acc[mi][ni], 0, 0, 0);
    if (s + 1 < nsteps) {
      __syncthreads();
      cur ^= 1;
    }
  }

#pragma unroll
  for (int mi = 0; mi < 4; ++mi) {
    int row0 = m0 + wy * 64 + mi * 16 + quad * 4;
#pragma unroll
    for (int ni = 0; ni < NI; ++ni) {
      int col = n0 + wx * WN + ni * 16 + l15;
      float bb = BIAS ? bias[col] : 0.f;
#pragma unroll
      for (int r = 0; r < 4; ++r) {
        float v = acc[mi][ni][r] + bb;
        if (RELU) v = fmaxf(v, 0.f);
        int row = row0 + r;
        if (OUTMODE == 3) {
          if (col < 1024) {
            ((unsigned short*)Cv)[(size_t)row * QKS + col] = f2b(v);
          } else {
            ((unsigned short*)Cv2)[(size_t)row * 512 + (col - 1024)] = f2b(v);
          }
        } else {
          size_t off = (size_t)row * ldc + col;
          if (ACC) v += ((const float*)Cv)[off];
          if (OUTMODE == 1) ((unsigned short*)Cv)[off] = f2b(v);
          else              ((float*)Cv)[off] = v;
        }
      }
    }
  }
}

// ---------------- MFMA flash attention, no-max softmax ----------------
// Fold-paired (17 uniform iterations/block). P conversion via paired
// v_cvt_pk_bf16_f32; denominator accumulates unrounded f32 p.
#define PSTR 72
__global__ __launch_bounds__(256) void attn_mfma(const unsigned short* __restrict__ q,
    const unsigned short* __restrict__ k, const unsigned short* __restrict__ vt,
    unsigned short* __restrict__ o) {
  __shared__ unsigned short Pbuf[2][64 * PSTR];
  __shared__ float Lsum[4][64];
  const int bh = blockIdx.y;
  const int b = bh >> 3, hh = bh & 7;
  const int tid = threadIdx.x;
  const int lane = tid & 63, w = tid >> 6;
  const int l15 = lane & 15, quad = lane >> 4;
  const float CEXP = 0.044194173824159216f * 1.4426950408889634f;  // scale*log2(e)

  const unsigned short* kbase = k  + (size_t)(b * T_ + w * 16 + l15) * QKS + hh * HS_ + quad * 8;
  const unsigned short* vbase = vt + ((size_t)(bh * HS_ + w * 16 + l15)) * T_ + quad * 8;
  const int gc = w * 16 + l15;
  const f32x4 z4 = {0.f, 0.f, 0.f, 0.f};

  for (int pass = 0; pass < 2; ++pass) {
    const int qt = pass ? (int)blockIdx.x : (T_ / 64 - 1 - (int)blockIdx.x);

    bf16x8 qf[4][2];
#pragma unroll
    for (int mi = 0; mi < 4; ++mi)
#pragma unroll
      for (int c = 0; c < 2; ++c)
        qf[mi][c] = *(const bf16x8*)(q + (size_t)(b * T_ + qt * 64 + mi * 16 + l15) * QKS
                                       + hh * HS_ + c * 32 + quad * 8);

    f32x4 oacc[4];
    float psum[4][4];
#pragma unroll
    for (int mi = 0; mi < 4; ++mi) {
      oacc[mi] = z4;
#pragma unroll
      for (int r = 0; r < 4; ++r) psum[mi][r] = 0.f;
    }

    bf16x8 kf[2], vf[2];
#pragma unroll
    for (int c = 0; c < 2; ++c) {
      kf[c] = *(const bf16x8*)(kbase + c * 32);
      vf[c] = *(const bf16x8*)(vbase + c * 32);
    }

    for (int kt = 0; kt <= qt; ++kt) {
      const int ktn = (kt < qt) ? kt + 1 : qt;
      bf16x8 kfn[2], vfn[2];
#pragma unroll
      for (int c = 0; c < 2; ++c) {
        kfn[c] = *(const bf16x8*)(kbase + (size_t)ktn * 64 * QKS + c * 32);
        vfn[c] = *(const bf16x8*)(vbase + ktn * 64 + c * 32);
      }

      f32x4 s[4];
#pragma unroll
      for (int mi = 0; mi < 4; ++mi) s[mi] = z4;
      __builtin_amdgcn_s_setprio(1);
#pragma unroll
      for (int c = 0; c < 2; ++c)
#pragma unroll
        for (int mi = 0; mi < 4; ++mi)
          s[mi] = __builtin_amdgcn_mfma_f32_16x16x32_bf16(qf[mi][c], kf[c], s[mi], 0, 0, 0);
      __builtin_amdgcn_s_setprio(0);

      unsigned short* pb = Pbuf[kt & 1];
      const bool diag = (kt == qt);
#pragma unroll
      for (int mi = 0; mi < 4; ++mi) {
        const int row0 = mi * 16 + quad * 4;
        float pv_[4];
#pragma unroll
        for (int r = 0; r < 4; ++r) {
          float p = exp2f(s[mi][r] * CEXP);
          if (diag && gc > row0 + r) p = 0.f;
          psum[mi][r] += p;
          pv_[r] = p;
        }
        unsigned pk01, pk23;
        asm("v_cvt_pk_bf16_f32 %0, %1, %2" : "=v"(pk01) : "v"(pv_[0]), "v"(pv_[1]));
        asm("v_cvt_pk_bf16_f32 %0, %1, %2" : "=v"(pk23) : "v"(pv_[2]), "v"(pv_[3]));
        const int base = row0 * PSTR + gc;
        pb[base]            = (unsigned short)(pk01 & 0xFFFFu);
        pb[base + PSTR]     = (unsigned short)(pk01 >> 16);
        pb[base + 2 * PSTR] = (unsigned short)(pk23 & 0xFFFFu);
        pb[base + 3 * PSTR] = (unsigned short)(pk23 >> 16);
      }
      __syncthreads();
      __builtin_amdgcn_s_setprio(1);
#pragma unroll
      for (int c = 0; c < 2; ++c) {
#pragma unroll
        for (int mi = 0; mi < 4; ++mi) {
          bf16x8 pf = *(const bf16x8*)(&pb[(mi * 16 + l15) * PSTR + c * 32 + quad * 8]);
          oacc[mi] = __builtin_amdgcn_mfma_f32_16x16x32_bf16(pf, vf[c], oacc[mi], 0, 0, 0);
        }
      }
      __builtin_amdgcn_s_setprio(0);
#pragma unroll
      for (int c = 0; c < 2; ++c) { kf[c] = kfn[c]; vf[c] = vfn[c]; }
    }

#pragma unroll
    for (int mi = 0; mi < 4; ++mi)
#pragma unroll
      for (int r = 0; r < 4; ++r) {
#pragma unroll
        for (int off = 1; off < 16; off <<= 1)
          psum[mi][r] += __shfl_xor(psum[mi][r], off, 64);
      }
    if (l15 == 0) {
#pragma unroll
      for (int mi = 0; mi < 4; ++mi)
#pragma unroll
        for (int r = 0; r < 4; ++r)
          Lsum[w][mi * 16 + quad * 4 + r] = psum[mi][r];
    }
    __syncthreads();
#pragma unroll
    for (int mi = 0; mi < 4; ++mi)
#pragma unroll
      for (int r = 0; r < 4; ++r) {
        int row = mi * 16 + quad * 4 + r;
        float inv = 1.f / (Lsum[0][row] + Lsum[1][row] + Lsum[2][row] + Lsum[3][row]);
        o[(size_t)(b * T_ + qt * 64 + row) * D_ + hh * HS_ + w * 16 + l15] =
            f2b(oacc[mi][r] * inv);
      }
  }
}

// ---------------- f32 tiled GEMM (logits only) ----------------
__global__ __launch_bounds__(256) void gemm_f32_kernel(const float* __restrict__ A, int lda,
    const float* __restrict__ Bw, int ldb, const float* __restrict__ bias,
    float* __restrict__ C, int ldc, int K, int N) {
  __shared__ float As[16][64];
  __shared__ float Bs[16][64];
  int n0 = blockIdx.y * 64;
  int nv = N - n0; if (nv > 64) nv = 64;
  int m0 = blockIdx.x * 64;
  const int tid = threadIdx.x;
  const int tx = tid & 15, ty = tid >> 4;
  const int amm = tid >> 2;
  const int akk = (tid & 3) * 4;
  const int bkk = tid >> 4;
  const int bnn = (tid & 15) * 4;
  float acc[4][4] = {};
  for (int k0 = 0; k0 < K; k0 += 16) {
    float4 av = *(const float4*)(A + (size_t)(m0 + amm) * lda + k0 + akk);
    As[akk + 0][amm] = av.x; As[akk + 1][amm] = av.y;
    As[akk + 2][amm] = av.z; As[akk + 3][amm] = av.w;
    if (bnn < nv) {
      float4 bv = *(const float4*)(Bw + (size_t)(k0 + bkk) * ldb + n0 + bnn);
      Bs[bkk][bnn + 0] = bv.x; Bs[bkk][bnn + 1] = bv.y;
      Bs[bkk][bnn + 2] = bv.z; Bs[bkk][bnn + 3] = bv.w;
    } else {
      Bs[bkk][bnn + 0] = 0.f; Bs[bkk][bnn + 1] = 0.f;
      Bs[bkk][bnn + 2] = 0.f; Bs[bkk][bnn + 3] = 0.f;
    }
    __syncthreads();
#pragma unroll
    for (int kk = 0; kk < 16; ++kk) {
      float4 a4 = *(const float4*)(&As[kk][ty * 4]);
      float4 b4 = *(const float4*)(&Bs[kk][tx * 4]);
      float aa[4] = {a4.x, a4.y, a4.z, a4.w};
      float bb[4] = {b4.x, b4.y, b4.z, b4.w};
#pragma unroll
      for (int i = 0; i < 4; ++i)
#pragma unroll
        for (int j = 0; j < 4; ++j)
          acc[i][j] = fmaf(aa[i], bb[j], acc[i][j]);
    }
    __syncthreads();
  }
  if (tx * 4 < nv) {
#pragma unroll
    for (int i = 0; i < 4; ++i) {
      float* cp = C + (size_t)(m0 + ty * 4 + i) * ldc + n0 + tx * 4;
      float4 st = {acc[i][0] + bias[n0 + tx * 4 + 0], acc[i][1] + bias[n0 + tx * 4 + 1],
                   acc[i][2] + bias[n0 + tx * 4 + 2], acc[i][3] + bias[n0 + tx * 4 + 3]};
      *(float4*)cp = st;
    }
  }
}

// ---------------- loss ----------------
__global__ __launch_bounds__(256) void loss_kernel(const float* __restrict__ logits,
    const int* __restrict__ targets, float* __restrict__ loss_acc) {
  __shared__ float wsum[4];
  int wave = threadIdx.x >> 6, lane = threadIdx.x & 63;
  float local = 0.f;
  for (int r = blockIdx.x * 4 + wave; r < BT_; r += gridDim.x * 4) {
    const float* lr = logits + (size_t)r * V_;
    float v0 = lr[lane];
    float v1 = (lane < 32) ? lr[64 + lane] : -INFINITY;
    float mx = fmaxf(v0, v1);
#pragma unroll
    for (int o = 32; o > 0; o >>= 1) mx = fmaxf(mx, __shfl_xor(mx, o, 64));
    float se = expf(v0 - mx) + ((lane < 32) ? expf(v1 - mx) : 0.f);
#pragma unroll
    for (int o = 32; o > 0; o >>= 1) se += __shfl_xor(se, o, 64);
    if (lane == 0) {
      int tg = targets[r];
      if (tg < 0) tg = 0; if (tg > V_ - 1) tg = V_ - 1;
      local += (mx + logf(se)) - lr[tg];
    }
  }
  if (lane == 0) wsum[wave] = local;
  __syncthreads();
  if (threadIdx.x == 0)
    atomicAdd(loss_acc, wsum[0] + wsum[1] + wsum[2] + wsum[3]);
}

__global__ void loss_finalize_kernel(const float* __restrict__ acc, float* __restrict__ out) {
  out[(size_t)BT_ * V_] = acc[0] * (1.f / BT_);
}

// ---------------- host ----------------
static void* g_ws_fallback = nullptr;

extern "C" void kernel_launch(void* const* d_in, const int* in_sizes, int n_in,
                              void* d_out, int out_size, void* d_ws, size_t ws_size,
                              hipStream_t stream) {
  const int*   idx     = (const int*)d_in[0];
  const int*   targets = (const int*)d_in[1];
  const float* tok  = (const float*)d_in[2];
  const float* pos  = (const float*)d_in[3];
  const float* Wq   = (const float*)d_in[4];
  const float* Wk   = (const float*)d_in[5];
  const float* Wv   = (const float*)d_in[6];
  const float* Wp   = (const float*)d_in[7];
  const float* bp   = (const float*)d_in[8];
  const float* W1   = (const float*)d_in[9];
  const float* b1   = (const float*)d_in[10];
  const float* W2   = (const float*)d_in[11];
  const float* b2   = (const float*)d_in[12];
  const float* l1s  = (const float*)d_in[13];
  const float* l1b  = (const float*)d_in[14];
  const float* l2s  = (const float*)d_in[15];
  const float* l2b  = (const float*)d_in[16];
  const float* lfs  = (const float*)d_in[17];
  const float* lfb  = (const float*)d_in[18];
  const float* Wout = (const float*)d_in[19];
  const float* bout = (const float*)d_in[20];
  float* out = (float*)d_out;   // f32 logits + f32 loss scalar

  const size_t n_x  = (size_t)BT_ * D_;
  const size_t n_wT = 9437184;   // transposed bf16 weights (f32-equiv)
  const size_t need_floats = n_x + n_x + n_x / 2 + n_x / 2 + n_x / 2 +
                             (size_t)BT_ * FF_ / 2 + n_wT + 256;
  const size_t need_bytes  = need_floats * sizeof(float);

  float* ws;
  if (ws_size >= need_bytes) {
    ws = (float*)d_ws;
  } else {
    if (!g_ws_fallback) (void)hipMalloc(&g_ws_fallback, need_bytes);
    ws = (float*)g_ws_fallback;
  }

  size_t off = 0;
  float* x  = ws + off; off += n_x;
  float* qf32 = ws + off; off += n_x;          // Q|K interleaved bf16 [BT][1024]; reused f32 final-LN
  unsigned short* qkb = (unsigned short*)qf32;
  unsigned short* vb  = (unsigned short*)(ws + off); off += n_x / 2;  // coalesced V [BT][512]
  unsigned short* vtb = (unsigned short*)(ws + off); off += n_x / 2;
  unsigned short* hb  = (unsigned short*)(ws + off); off += n_x / 2;
  unsigned short* ffb = (unsigned short*)(ws + off); off += (size_t)BT_ * FF_ / 2;
  unsigned short* wqkvT = (unsigned short*)(ws + off);   // per-layer [1536][512]
  unsigned short* wpT = wqkvT + (size_t)L_ * 3 * D_ * D_;
  unsigned short* w1T = wpT + (size_t)L_ * D_ * D_;
  unsigned short* w2T = w1T + (size_t)L_ * D_ * FF_;
  off += n_wT;
  float* lacc = ws + off;

  const long DD = (long)D_ * D_;          // 262144
  const long L3DD = 3 * DD;               // per-layer combined QKV stride

  zero_kernel<<<1, 1, 0, stream>>>(lacc);
  embed_kernel<<<BT_, 128, 0, stream>>>(idx, tok, pos, x);

  // combined QKV weight transpose: layer l rows [0,512)=Q, [512,1024)=K, [1024,1536)=V
  transpose_cvt<<<dim3(2, 16, 48), 256, 0, stream>>>(Wq, wqkvT,            512, 64, 32768, 32768, 8, L3DD);
  transpose_cvt<<<dim3(2, 16, 48), 256, 0, stream>>>(Wk, wqkvT + DD,       512, 64, 32768, 32768, 8, L3DD);
  transpose_cvt<<<dim3(2, 16, 48), 256, 0, stream>>>(Wv, wqkvT + 2 * DD,   512, 64, 32768, 32768, 8, L3DD);
  transpose_cvt<<<dim3(16, 16, 6), 256, 0, stream>>>(Wp, wpT, 512, 512, 262144, 0, 1, 262144);
  transpose_cvt<<<dim3(64, 16, 6), 256, 0, stream>>>(W1, w1T, 512, 2048, 1048576, 0, 1, 1048576);
  transpose_cvt<<<dim3(16, 64, 6), 256, 0, stream>>>(W2, w2T, 2048, 512, 1048576, 0, 1, 1048576);

  const dim3 gQKV(BT_ / 128, 12);         // 768 blocks, 128x128
  const dim3 gF(BT_ / 128, FF_ / 128);    // 1024 blocks, 128x128
  const dim3 gD64(BT_ / 64, D_ / 128);    // 512 blocks, 64x128 (proj/FF2)
  const dim3 gVT(512 / 32, T_ / 32, B_);  // per-batch [T][512] -> [512][T]

  for (int l = 0; l < L_; ++l) {
    ln_kernel<true><<<BT_ / 4, 256, 0, stream>>>(x, l1s + (size_t)l * D_, l1b + (size_t)l * D_, hb);
    mfma_gemm<false, false, false, 3, 128, 128><<<gQKV, 256, 0, stream>>>(
        hb, wqkvT + (size_t)l * L3DD, nullptr, qkb, vb, D_, 0);
    vtrans_kernel<<<gVT, 256, 0, stream>>>(vb, vtb);
    attn_mfma<<<dim3(T_ / 128, B_ * H_), 256, 0, stream>>>(qkb, qkb + 512, vtb, hb);
    mfma_gemm<true, false, true, 0, 64, 128><<<gD64, 256, 0, stream>>>(
        hb, wpT + (size_t)l * DD, bp + (size_t)l * D_, x, nullptr, D_, D_);
    ln_kernel<true><<<BT_ / 4, 256, 0, stream>>>(x, l2s + (size_t)l * D_, l2b + (size_t)l * D_, hb);
    mfma_gemm<false, true, true, 1, 128, 128><<<gF, 256, 0, stream>>>(
        hb, w1T + (size_t)l * D_ * FF_, b1 + (size_t)l * FF_, ffb, nullptr, D_, FF_);
    mfma_gemm<true, false, true, 0, 64, 128><<<gD64, 256, 0, stream>>>(
        ffb, w2T + (size_t)l * FF_ * D_, b2 + (size_t)l * D_, x, nullptr, FF_, D_);
  }

  ln_kernel<false><<<BT_ / 4, 256, 0, stream>>>(x, lfs, lfb, qf32);
  gemm_f32_kernel<<<dim3(BT_ / 64, 2), 256, 0, stream>>>(
      qf32, D_, Wout, V_, bout, out, V_, D_, V_);
  loss_kernel<<<1024, 256, 0, stream>>>(out, targets, lacc);
  loss_finalize_kernel<<<1, 1, 0, stream>>>(lacc, out);
}